// Round 11
// baseline (83.971 us; speedup 1.0000x reference)
//
#include <hip/hip_runtime.h>
#include <hip/hip_bf16.h>

// ---------------------------------------------------------------------------
// PGAConjugateLinear as bf16 MFMA GEMM + bias.
//   out[b, n=o*3+p] = sum_{k=i*3+r} bf16(x[b][k]) * Bw[n][k]  +  bias[n]
//   Bw[n][k] = weight[o,i] * T_oi[p][r]   (bf16, B^T layout, r in 0..2)
//   bias[n]  = sum_i weight[o,i] * T_oi[p][3] * e0[i]
// GEMM: M=4096, N=1536, K=1536. R5-proven structure: tile 64x128, BK=64,
// 8 waves (2x4) of 32x32, grid 768 = exactly 3 blocks/CU, XCD-chunked,
// stage-early + __syncthreads double buffer (2-phase; every fancier schedule
// R6/R7/R9/R10 regressed).
// NEW: A is REG-STAGED from fp32 x directly (pack_x kernel eliminated):
// thread loads 2x float4 (issued before COMPUTE; MFMA hides HBM latency),
// 4x v_cvt_pk_bf16_f32, one ds_write_b128 into the stripe-transpose slot
// layout (ds_write has no linear-dest constraint). Saves the A round trip
// (12.6 MB write + 12.6 MB read) and one kernel launch.
// LDS stripe-transpose: slot(row,g) = (row>>3)*64 + g*8 + (row&7); 16B slots;
// conflict-free ds_read_b128 (0 conflicts verified R6-R9).
// ---------------------------------------------------------------------------

#define B_DIM 4096
#define I_DIM 512
#define O_DIM 512
#define N_DIM (O_DIM * 3)   // 1536
#define K_DIM (I_DIM * 3)   // 1536
#define BK 64
#define NT (K_DIM / BK)     // 24 K-steps

typedef __attribute__((ext_vector_type(8))) short bf16x8;
typedef __attribute__((ext_vector_type(4))) float f32x4;

__device__ __forceinline__ unsigned short f2bf(float f) {
    unsigned u = __float_as_uint(f);
    unsigned r = (u + 0x7fffu + ((u >> 16) & 1u)) >> 16;  // RNE
    return (unsigned short)r;
}

__device__ __forceinline__ void gload_lds16(const void* g, void* l) {
    __builtin_amdgcn_global_load_lds(
        (const __attribute__((address_space(1))) unsigned*)g,
        (__attribute__((address_space(3))) unsigned*)l, 16, 0, 0);
}

// Cayley table for Cl(3,0,1), metric [0,1,1,1], reference blade order.
struct Cayley {
    float M[16][16][16];
    float rev[16];
    constexpr Cayley() : M{}, rev{} {
        const unsigned masks[16] = {0u, 1u, 2u, 4u, 8u, 3u, 5u, 9u, 6u, 10u,
                                    12u, 7u, 11u, 13u, 14u, 15u};
        int idx_of[16] = {};
        for (int i = 0; i < 16; ++i) idx_of[masks[i]] = i;
        const int metric[4] = {0, 1, 1, 1};
        for (int i = 0; i < 16; ++i) {
            unsigned a = masks[i];
            for (int j = 0; j < 16; ++j) {
                unsigned b = masks[j];
                int swaps = 0;
                for (int jb = 0; jb < 4; ++jb)
                    if ((b >> jb) & 1u)
                        for (int ia = jb + 1; ia < 4; ++ia)
                            if ((a >> ia) & 1u) ++swaps;
                int sign = (swaps & 1) ? -1 : 1;
                unsigned common = a & b;
                for (int g = 0; g < 4; ++g)
                    if ((common >> g) & 1u) sign *= metric[g];
                if (sign != 0) M[i][j][idx_of[a ^ b]] += (float)sign;
            }
            int grade = 0;
            for (int g = 0; g < 4; ++g) grade += (int)((a >> g) & 1u);
            rev[i] = ((grade * (grade - 1) / 2) % 2) ? -1.f : 1.f;
        }
    }
};
constexpr Cayley CAY{};

// ---------------------------------------------------------------------------
// prep (build-only now): one block per o. Bw rows (bf16) + bias (block-reduce).
// ---------------------------------------------------------------------------
__global__ __launch_bounds__(256) void prep(const float* __restrict__ weight,
                                            const float* __restrict__ action,
                                            const float* __restrict__ e0,
                                            unsigned short* __restrict__ Bw,
                                            float* __restrict__ bias) {
    const int o = blockIdx.x;
    const int tid = threadIdx.x;
    const int wave = tid >> 6, lane = tid & 63;
    __shared__ float red[4][3];

    constexpr int AB[8] = {0, 5, 6, 7, 8, 9, 10, 15};
    constexpr int PB[3] = {11, 12, 13};
    constexpr int RB[4] = {11, 12, 13, 14};

    float sb[3] = {0.f, 0.f, 0.f};

#pragma unroll
    for (int s = 0; s < 2; ++s) {
        const int i = tid * 2 + s;
        const int t = o * I_DIM + i;

        float a[8];
        const float* ap = action + (size_t)t * 8;
#pragma unroll
        for (int j = 0; j < 8; ++j) a[j] = ap[j];

        float kv[16], kr[16];
#pragma unroll
        for (int j = 0; j < 16; ++j) { kv[j] = 0.f; kr[j] = 0.f; }
#pragma unroll
        for (int j = 0; j < 8; ++j) {
            kv[AB[j]] = a[j];
            kr[AB[j]] = a[j] * CAY.rev[AB[j]];
        }

        float Am[3][16];
#pragma unroll
        for (int pp = 0; pp < 3; ++pp)
#pragma unroll
            for (int q = 0; q < 16; ++q) {
                float sum = 0.f;
#pragma unroll
                for (int tt = 0; tt < 16; ++tt) sum += CAY.M[q][PB[pp]][tt] * kr[tt];
                Am[pp][q] = sum;
            }

        float Bm[16][4];
#pragma unroll
        for (int q = 0; q < 16; ++q)
#pragma unroll
            for (int rr = 0; rr < 4; ++rr) {
                float sum = 0.f;
#pragma unroll
                for (int m = 0; m < 16; ++m) sum += CAY.M[m][q][RB[rr]] * kv[m];
                Bm[q][rr] = sum;
            }

        const float w = weight[t];
        const float e0i = e0[i];
#pragma unroll
        for (int pp = 0; pp < 3; ++pp) {
            float r0 = 0.f, r1 = 0.f, r2 = 0.f, r3 = 0.f;
#pragma unroll
            for (int q = 0; q < 16; ++q) {
                r0 += Am[pp][q] * Bm[q][0];
                r1 += Am[pp][q] * Bm[q][1];
                r2 += Am[pp][q] * Bm[q][2];
                r3 += Am[pp][q] * Bm[q][3];
            }
            unsigned short* bp = Bw + (size_t)(o * 3 + pp) * K_DIM + i * 3;
            bp[0] = f2bf(w * r0);
            bp[1] = f2bf(w * r1);
            bp[2] = f2bf(w * r2);
            sb[pp] += w * r3 * e0i;
        }
    }

#pragma unroll
    for (int off = 32; off; off >>= 1) {
#pragma unroll
        for (int pp = 0; pp < 3; ++pp) sb[pp] += __shfl_down(sb[pp], off, 64);
    }
    if (lane == 0) {
#pragma unroll
        for (int pp = 0; pp < 3; ++pp) red[wave][pp] = sb[pp];
    }
    __syncthreads();
    if (tid == 0) {
#pragma unroll
        for (int pp = 0; pp < 3; ++pp)
            bias[o * 3 + pp] = red[0][pp] + red[1][pp] + red[2][pp] + red[3][pp];
    }
}

// ---------------------------------------------------------------------------
// gemm: C[m][n] = sum_k bf16(x[m][k])*Bw[n][k] + bias[n].
// ---------------------------------------------------------------------------
__global__ __launch_bounds__(512, 6) void gemm_bf16(
        const float* __restrict__ x,
        const unsigned short* __restrict__ Bw,
        const float* __restrict__ bias,
        float* __restrict__ C) {
    __shared__ unsigned short As0[64 * 64], As1[64 * 64];    //  8 KB each
    __shared__ unsigned short Bs0[128 * 64], Bs1[128 * 64];  // 16 KB each
    // 48 KB total -> 3 blocks/CU at 512 threads (24 waves/CU).

    const int tid = threadIdx.x;
    const int wave = tid >> 6, lane = tid & 63;

    // XCD-chunked bijective swizzle (768 % 8 == 0), m-tile-major in chunk.
    const int bid = blockIdx.x;
    const int swz = (bid & 7) * 96 + (bid >> 3);
    const int mt = swz / 12, nt = swz - mt * 12;
    const int m0 = mt * 64, n0 = nt * 128;
    const int wr = wave >> 2, wc = wave & 3;    // 2x4 wave grid, 32x32 each

    // slot decode (shared by A and B): slot s -> row=(s>>6)*8+(s&7), g=(s>>3)&7
    const int sRow = ((tid >> 6) * 8) + (tid & 7);
    const int sG = (tid >> 3) & 7;

    // A reg-staging source: fp32 x, 8 floats at (m0+sRow, k = t*BK + sG*8)
    const float* aSrc = x + (size_t)(m0 + sRow) * K_DIM + sG * 8;

    // B staging (global_load_lds, as R5): slots tid and tid+512
    const unsigned short* bSrc0 = Bw + (size_t)(n0 + sRow) * K_DIM + sG * 8;
    const unsigned short* bSrc1 = bSrc0 + (size_t)64 * K_DIM;  // slot+512=row+64
    const int b1off = (tid + 512) * 8;

    // fragment read offsets (shorts): slot(r,g)*8, g = kh*4 + (lane>>4)
    const int frow = lane & 15;
    const int gl = lane >> 4;
    int aro[2][2], bro[2][2];
#pragma unroll
    for (int kh = 0; kh < 2; ++kh) {
        const int g = kh * 4 + gl;
#pragma unroll
        for (int mi = 0; mi < 2; ++mi) {
            const int r = wr * 32 + mi * 16 + frow;
            aro[kh][mi] = (((r >> 3) * 64) + g * 8 + (r & 7)) * 8;
        }
#pragma unroll
        for (int ni = 0; ni < 2; ++ni) {
            const int r = wc * 32 + ni * 16 + frow;
            bro[kh][ni] = (((r >> 3) * 64) + g * 8 + (r & 7)) * 8;
        }
    }

    f32x4 acc[2][2] = {};

    // A: issue fp32 loads (compiler inserts the vmcnt before first use in
    // AWRITE, so placing ALOAD before COMPUTE hides the HBM latency there).
#define ALOAD(VA, VB, T)                                        \
    do {                                                        \
        (VA) = *(const float4*)(aSrc + (size_t)(T) * BK);       \
        (VB) = *(const float4*)(aSrc + (size_t)(T) * BK + 4);   \
    } while (0)

    // cvt_pk (src0 -> low half) + one ds_write_b128 to slot tid.
#define AWRITE(AS, VA, VB)                                                   \
    do {                                                                     \
        unsigned r0, r1, r2, r3;                                             \
        asm("v_cvt_pk_bf16_f32 %0, %1, %2" : "=v"(r0) : "v"((VA).x), "v"((VA).y)); \
        asm("v_cvt_pk_bf16_f32 %0, %1, %2" : "=v"(r1) : "v"((VA).z), "v"((VA).w)); \
        asm("v_cvt_pk_bf16_f32 %0, %1, %2" : "=v"(r2) : "v"((VB).x), "v"((VB).y)); \
        asm("v_cvt_pk_bf16_f32 %0, %1, %2" : "=v"(r3) : "v"((VB).z), "v"((VB).w)); \
        uint4 u;                                                             \
        u.x = r0; u.y = r1; u.z = r2; u.w = r3;                              \
        *(uint4*)&(AS)[tid * 8] = u;                                         \
    } while (0)

#define STAGE_B(BS, T)                                              \
    do {                                                            \
        gload_lds16(bSrc0 + (size_t)(T) * BK, (BS) + tid * 8);      \
        gload_lds16(bSrc1 + (size_t)(T) * BK, (BS) + b1off);        \
    } while (0)

#define COMPUTE(AS, BS)                                                   \
    do {                                                                  \
        bf16x8 af[2][2], bv[2][2];                                        \
        _Pragma("unroll")                                                 \
        for (int kh = 0; kh < 2; ++kh) {                                  \
            _Pragma("unroll")                                             \
            for (int mi = 0; mi < 2; ++mi)                                \
                af[kh][mi] = *(const bf16x8*)&(AS)[aro[kh][mi]];          \
            _Pragma("unroll")                                             \
            for (int ni = 0; ni < 2; ++ni)                                \
                bv[kh][ni] = *(const bf16x8*)&(BS)[bro[kh][ni]];          \
        }                                                                 \
        _Pragma("unroll")                                                 \
        for (int kh = 0; kh < 2; ++kh)                                    \
            _Pragma("unroll")                                             \
            for (int mi = 0; mi < 2; ++mi)                                \
                _Pragma("unroll")                                         \
                for (int ni = 0; ni < 2; ++ni)                            \
                    acc[mi][ni] = __builtin_amdgcn_mfma_f32_16x16x32_bf16(\
                        af[kh][mi], bv[kh][ni], acc[mi][ni], 0, 0, 0);    \
    } while (0)

    float4 va0, vb0, va1, vb1;

    // prologue: tile 0 (A load stalls once on vmcnt here; that's fine)
    ALOAD(va0, vb0, 0);
    STAGE_B(Bs0, 0);
    AWRITE(As0, va0, vb0);
    __syncthreads();                       // drains B gload_lds + ds_write

#pragma unroll 1
    for (int t = 0; t < NT - 2; t += 2) {
        ALOAD(va1, vb1, t + 1);            // issue next-tile loads FIRST
        STAGE_B(Bs1, t + 1);
        COMPUTE(As0, Bs0);                 // MFMA hides A-reg + B-lds latency
        AWRITE(As1, va1, vb1);             // As1 last read before prev sync
        __syncthreads();
        ALOAD(va0, vb0, t + 2);
        STAGE_B(Bs0, t + 2);
        COMPUTE(As1, Bs1);
        AWRITE(As0, va0, vb0);
        __syncthreads();
    }
    ALOAD(va1, vb1, NT - 1);
    STAGE_B(Bs1, NT - 1);
    COMPUTE(As0, Bs0);
    AWRITE(As1, va1, vb1);
    __syncthreads();
    COMPUTE(As1, Bs1);

#undef ALOAD
#undef AWRITE
#undef STAGE_B
#undef COMPUTE

    // epilogue: C/D layout col = lane&15, row = (lane>>4)*4 + j; add bias[n]
    const int crow = (lane >> 4) * 4;
    const int ccol = lane & 15;
#pragma unroll
    for (int mi = 0; mi < 2; ++mi)
#pragma unroll
        for (int ni = 0; ni < 2; ++ni) {
            const int n = n0 + wc * 32 + ni * 16 + ccol;
            const float bv = bias[n];
            float* cp = C + (size_t)(m0 + wr * 32 + mi * 16 + crow) * N_DIM + n;
#pragma unroll
            for (int j = 0; j < 4; ++j) cp[(size_t)j * N_DIM] = acc[mi][ni][j] + bv;
        }
}

// ---------------------------------------------------------------------------
extern "C" void kernel_launch(void* const* d_in, const int* in_sizes, int n_in,
                              void* d_out, int out_size, void* d_ws, size_t ws_size,
                              hipStream_t stream) {
    const float* x      = (const float*)d_in[0];  // (4096, 512, 3)
    const float* weight = (const float*)d_in[1];  // (512, 512)
    const float* action = (const float*)d_in[2];  // (512, 512, 8)
    const float* e0     = (const float*)d_in[3];  // (512, 1)
    float* out = (float*)d_out;                   // (4096, 512, 3)

    unsigned short* Bw = (unsigned short*)d_ws;                 // 4.7 MB
    float* bias = (float*)(Bw + (size_t)N_DIM * K_DIM);         // 1536 f32

    hipLaunchKernelGGL(prep, dim3(O_DIM), dim3(256), 0, stream,
                       weight, action, e0, Bw, bias);
    hipLaunchKernelGGL(gemm_bf16, dim3(768), dim3(512), 0, stream,
                       x, Bw, bias, out);
}

// Round 12
// 43.060 us; speedup vs baseline: 1.9501x; 1.9501x over previous
//
#include <hip/hip_runtime.h>
#include <hip/hip_bf16.h>

// ---------------------------------------------------------------------------
// PGAConjugateLinear as bf16 MFMA GEMM + bias.  CONSOLIDATION ROUND:
// R5's gemm (best measured, 44.7 us total) + R6's fused prep (proven).
//   out[b, n=o*3+p] = sum_{k=i*3+r} A[b][k] * Bw[n][k]  +  bias[n]
//   A[b][k]  = bf16(x[b][k])              (x is (4096,512,3) contiguous)
//   Bw[n][k] = weight[o,i] * T_oi[p][r]   (bf16, B^T layout, r in 0..2)
//   bias[n]  = sum_i weight[o,i] * T_oi[p][3] * e0[i]
// GEMM: M=4096, N=1536, K=1536. Tile 64x128, BK=64, 8 waves (2x4, 32x32),
// grid 768 = exactly 3 blocks/CU (24 waves/CU), XCD-chunked swizzle,
// both-sides XOR LDS swizzle, stage-early + __syncthreads double buffer.
// Failed alternatives (R6-R11): BK=32 3-buf counted-vmcnt, BK=64 counted-
// vmcnt, k-split waves (VGPR spill), 4-wave 2-block (TLP loss), 8-phase port
// (1 block/CU), reg-staged A (lgkmcnt serialization). Do not revisit.
// ---------------------------------------------------------------------------

#define B_DIM 4096
#define I_DIM 512
#define O_DIM 512
#define N_DIM (O_DIM * 3)   // 1536
#define K_DIM (I_DIM * 3)   // 1536
#define NT (K_DIM / 64)     // 24 K-steps

typedef __attribute__((ext_vector_type(8))) short bf16x8;
typedef __attribute__((ext_vector_type(4))) float f32x4;

__device__ __forceinline__ unsigned short f2bf(float f) {
    unsigned u = __float_as_uint(f);
    unsigned r = (u + 0x7fffu + ((u >> 16) & 1u)) >> 16;  // RNE
    return (unsigned short)r;
}

__device__ __forceinline__ void gload_lds16(const void* g, void* l) {
    __builtin_amdgcn_global_load_lds(
        (const __attribute__((address_space(1))) unsigned*)g,
        (__attribute__((address_space(3))) unsigned*)l, 16, 0, 0);
}

// Cayley table for Cl(3,0,1), metric [0,1,1,1], reference blade order.
struct Cayley {
    float M[16][16][16];
    float rev[16];
    constexpr Cayley() : M{}, rev{} {
        const unsigned masks[16] = {0u, 1u, 2u, 4u, 8u, 3u, 5u, 9u, 6u, 10u,
                                    12u, 7u, 11u, 13u, 14u, 15u};
        int idx_of[16] = {};
        for (int i = 0; i < 16; ++i) idx_of[masks[i]] = i;
        const int metric[4] = {0, 1, 1, 1};
        for (int i = 0; i < 16; ++i) {
            unsigned a = masks[i];
            for (int j = 0; j < 16; ++j) {
                unsigned b = masks[j];
                int swaps = 0;
                for (int jb = 0; jb < 4; ++jb)
                    if ((b >> jb) & 1u)
                        for (int ia = jb + 1; ia < 4; ++ia)
                            if ((a >> ia) & 1u) ++swaps;
                int sign = (swaps & 1) ? -1 : 1;
                unsigned common = a & b;
                for (int g = 0; g < 4; ++g)
                    if ((common >> g) & 1u) sign *= metric[g];
                if (sign != 0) M[i][j][idx_of[a ^ b]] += (float)sign;
            }
            int grade = 0;
            for (int g = 0; g < 4; ++g) grade += (int)((a >> g) & 1u);
            rev[i] = ((grade * (grade - 1) / 2) % 2) ? -1.f : 1.f;
        }
    }
};
constexpr Cayley CAY{};

// ---------------------------------------------------------------------------
// prep: fused pack_x (blocks 0..1535) + build_w/bias (blocks 1536..2047).
// BW-bound pack blocks and VALU-bound build blocks co-schedule on CUs.
// ---------------------------------------------------------------------------
__global__ __launch_bounds__(512) void prep(const float* __restrict__ x,
                                            const float* __restrict__ weight,
                                            const float* __restrict__ action,
                                            const float* __restrict__ e0,
                                            unsigned short* __restrict__ A,
                                            unsigned short* __restrict__ Bw,
                                            float* __restrict__ bias) {
    const int bid = blockIdx.x;
    const int tid = threadIdx.x;

    if (bid < 1536) {
        // ---- pack: A = bf16(x), flat cast (k=i*3+r is exactly x's layout)
        const size_t t = (size_t)bid * 512 + tid;
        const float4* xp = (const float4*)(x + t * 8);
        const float4 v0 = xp[0], v1 = xp[1];
        const float xs[8] = {v0.x, v0.y, v0.z, v0.w, v1.x, v1.y, v1.z, v1.w};
        unsigned short ov[8];
#pragma unroll
        for (int q = 0; q < 8; ++q) ov[q] = f2bf(xs[q]);
        *(uint4*)(A + t * 8) = *(const uint4*)ov;   // 16B store
        return;
    }

    // ---- build: one block per o, one thread per i.
    const int o = bid - 1536;
    const int i = tid;
    const int t = o * I_DIM + i;
    const int wave = tid >> 6, lane = tid & 63;
    __shared__ float red[8][3];

    constexpr int AB[8] = {0, 5, 6, 7, 8, 9, 10, 15};
    constexpr int PB[3] = {11, 12, 13};
    constexpr int RB[4] = {11, 12, 13, 14};

    float a[8];
    const float* ap = action + (size_t)t * 8;
#pragma unroll
    for (int j = 0; j < 8; ++j) a[j] = ap[j];

    float kv[16], kr[16];
#pragma unroll
    for (int j = 0; j < 16; ++j) { kv[j] = 0.f; kr[j] = 0.f; }
#pragma unroll
    for (int j = 0; j < 8; ++j) {
        kv[AB[j]] = a[j];
        kr[AB[j]] = a[j] * CAY.rev[AB[j]];
    }

    float Am[3][16];
#pragma unroll
    for (int pp = 0; pp < 3; ++pp)
#pragma unroll
        for (int q = 0; q < 16; ++q) {
            float s = 0.f;
#pragma unroll
            for (int tt = 0; tt < 16; ++tt) s += CAY.M[q][PB[pp]][tt] * kr[tt];
            Am[pp][q] = s;
        }

    float Bm[16][4];
#pragma unroll
    for (int q = 0; q < 16; ++q)
#pragma unroll
        for (int rr = 0; rr < 4; ++rr) {
            float s = 0.f;
#pragma unroll
            for (int m = 0; m < 16; ++m) s += CAY.M[m][q][RB[rr]] * kv[m];
            Bm[q][rr] = s;
        }

    const float w = weight[t];
    const float e0i = e0[i];
    float sb[3];
#pragma unroll
    for (int pp = 0; pp < 3; ++pp) {
        float r0 = 0.f, r1 = 0.f, r2 = 0.f, r3 = 0.f;
#pragma unroll
        for (int q = 0; q < 16; ++q) {
            r0 += Am[pp][q] * Bm[q][0];
            r1 += Am[pp][q] * Bm[q][1];
            r2 += Am[pp][q] * Bm[q][2];
            r3 += Am[pp][q] * Bm[q][3];
        }
        unsigned short* bp = Bw + (size_t)(o * 3 + pp) * K_DIM + i * 3;
        bp[0] = f2bf(w * r0);
        bp[1] = f2bf(w * r1);
        bp[2] = f2bf(w * r2);
        sb[pp] = w * r3 * e0i;
    }

#pragma unroll
    for (int off = 32; off; off >>= 1) {
#pragma unroll
        for (int pp = 0; pp < 3; ++pp) sb[pp] += __shfl_down(sb[pp], off, 64);
    }
    if (lane == 0) {
#pragma unroll
        for (int pp = 0; pp < 3; ++pp) red[wave][pp] = sb[pp];
    }
    __syncthreads();
    if (tid == 0) {
#pragma unroll
        for (int pp = 0; pp < 3; ++pp) {
            float s = 0.f;
#pragma unroll
            for (int wv = 0; wv < 8; ++wv) s += red[wv][pp];
            bias[o * 3 + pp] = s;
        }
    }
}

// ---------------------------------------------------------------------------
// gemm (R5 byte-identical): C[m][n] = sum_k A[m][k]*Bw[n][k] + bias[n].
// Tile 64x128, BK=64, 8 waves (2x4, each 32x32). Double-buffered LDS.
// ---------------------------------------------------------------------------
__global__ __launch_bounds__(512, 6) void gemm_bf16(
        const unsigned short* __restrict__ A,
        const unsigned short* __restrict__ Bw,
        const float* __restrict__ bias,
        float* __restrict__ C) {
    __shared__ unsigned short As0[64 * 64], As1[64 * 64];    //  8 KB each
    __shared__ unsigned short Bs0[128 * 64], Bs1[128 * 64];  // 16 KB each

    const int tid = threadIdx.x;
    const int wave = tid >> 6, lane = tid & 63;

    // XCD-chunked bijective swizzle (768 % 8 == 0), m-tile-major.
    const int bid = blockIdx.x;
    const int swz = (bid & 7) * 96 + (bid >> 3);
    const int mt = swz / 12, nt = swz - mt * 12;
    const int m0 = mt * 64, n0 = nt * 128;
    const int wr = wave >> 2, wc = wave & 3;     // 2x4 wave grid, 32x32 each

    // staging: 16B segs; seg s -> LDS byte s*16 (linear); global col-seg
    // = (s&7)^(row&7)   [both-sides XOR swizzle]
    const int sA = tid;                                  // A: 512 segs (1/thread)
    const unsigned short* aSrc =
        A + (size_t)(m0 + (sA >> 3)) * K_DIM + (((sA & 7) ^ ((sA >> 3) & 7)) * 8);
    const int aOff = tid * 8;                            // short offset

    const unsigned short* bSrc[2];
    int bOff[2];
#pragma unroll
    for (int q = 0; q < 2; ++q) {
        const int s = tid + q * 512;                     // B: 1024 segs (2/thread)
        bSrc[q] = Bw + (size_t)(n0 + (s >> 3)) * K_DIM +
                  (((s & 7) ^ ((s >> 3) & 7)) * 8);
        bOff[q] = s * 8;
    }

    // fragment read: row r, global col-seg g -> elem r*64 + (g^(r&7))*8
    const int frow = lane & 15;
    const int g0 = lane >> 4;

    f32x4 acc[2][2] = {};

#define STAGE(AS, BS, K0)                                   \
    do {                                                    \
        gload_lds16(aSrc + (K0), (AS) + aOff);              \
        gload_lds16(bSrc[0] + (K0), (BS) + bOff[0]);        \
        gload_lds16(bSrc[1] + (K0), (BS) + bOff[1]);        \
    } while (0)

#define COMPUTE(AS, BS)                                                        \
    do {                                                                       \
        bf16x8 af[2][2], bfr[2][2];                                            \
        _Pragma("unroll")                                                      \
        for (int kh = 0; kh < 2; ++kh) {                                       \
            _Pragma("unroll")                                                  \
            for (int mi = 0; mi < 2; ++mi) {                                   \
                const int r = wr * 32 + mi * 16 + frow;                        \
                af[kh][mi] =                                                   \
                    *(const bf16x8*)&(AS)[r * 64 + ((g0 + kh * 4) ^ (r & 7)) * 8]; \
            }                                                                  \
            _Pragma("unroll")                                                  \
            for (int ni = 0; ni < 2; ++ni) {                                   \
                const int r = wc * 32 + ni * 16 + frow;                        \
                bfr[kh][ni] =                                                  \
                    *(const bf16x8*)&(BS)[r * 64 + ((g0 + kh * 4) ^ (r & 7)) * 8]; \
            }                                                                  \
        }                                                                      \
        _Pragma("unroll")                                                      \
        for (int kh = 0; kh < 2; ++kh)                                         \
            _Pragma("unroll")                                                  \
            for (int mi = 0; mi < 2; ++mi)                                     \
                _Pragma("unroll")                                              \
                for (int ni = 0; ni < 2; ++ni)                                 \
                    acc[mi][ni] = __builtin_amdgcn_mfma_f32_16x16x32_bf16(     \
                        af[kh][mi], bfr[kh][ni], acc[mi][ni], 0, 0, 0);        \
    } while (0)

    STAGE(As0, Bs0, 0);
    __syncthreads();                       // buf0 ready

#pragma unroll 1
    for (int t = 0; t < NT - 2; t += 2) {
        STAGE(As1, Bs1, (t + 1) * 64);     // issue next-tile loads FIRST
        COMPUTE(As0, Bs0);                 // MFMA + other waves hide latency
        __syncthreads();
        STAGE(As0, Bs0, (t + 2) * 64);
        COMPUTE(As1, Bs1);
        __syncthreads();
    }
    STAGE(As1, Bs1, (NT - 1) * 64);
    COMPUTE(As0, Bs0);
    __syncthreads();
    COMPUTE(As1, Bs1);

#undef STAGE
#undef COMPUTE

    // epilogue: C/D layout col = lane&15, row = (lane>>4)*4 + j; add bias[n]
    const int crow = (lane >> 4) * 4;
    const int ccol = lane & 15;
#pragma unroll
    for (int mi = 0; mi < 2; ++mi)
#pragma unroll
        for (int ni = 0; ni < 2; ++ni) {
            const int n = n0 + wc * 32 + ni * 16 + ccol;
            const float bv = bias[n];
            float* cp = C + (size_t)(m0 + wr * 32 + mi * 16 + crow) * N_DIM + n;
#pragma unroll
            for (int j = 0; j < 4; ++j) cp[(size_t)j * N_DIM] = acc[mi][ni][j] + bv;
        }
}

// ---------------------------------------------------------------------------
extern "C" void kernel_launch(void* const* d_in, const int* in_sizes, int n_in,
                              void* d_out, int out_size, void* d_ws, size_t ws_size,
                              hipStream_t stream) {
    const float* x      = (const float*)d_in[0];  // (4096, 512, 3)
    const float* weight = (const float*)d_in[1];  // (512, 512)
    const float* action = (const float*)d_in[2];  // (512, 512, 8)
    const float* e0     = (const float*)d_in[3];  // (512, 1)
    float* out = (float*)d_out;                   // (4096, 512, 3)

    unsigned short* Bw = (unsigned short*)d_ws;                 // 4.7 MB
    unsigned short* Ap = Bw + (size_t)N_DIM * K_DIM;            // 12.6 MB
    float* bias = (float*)(Ap + (size_t)B_DIM * K_DIM);         // 1536 f32

    hipLaunchKernelGGL(prep, dim3(2048), dim3(512), 0, stream,
                       x, weight, action, e0, Ap, Bw, bias);
    hipLaunchKernelGGL(gemm_bf16, dim3(768), dim3(512), 0, stream,
                       Ap, Bw, bias, out);
}

// Round 13
// 42.386 us; speedup vs baseline: 1.9811x; 1.0159x over previous
//
#include <hip/hip_runtime.h>
#include <hip/hip_bf16.h>

// ---------------------------------------------------------------------------
// PGAConjugateLinear as bf16 MFMA GEMM + bias.
//   out[b, n=o*3+p] = sum_{k=i*3+r} A[b][k] * Bw[n][k]  +  bias[n]
//   A[b][k]  = bf16(x[b][k]);  Bw[n][k] = weight*T[p][r];  bias from e123.
// GEMM: M=4096, N=1536, K=1536. Tile 64x128, BK=64, grid 768 = 3 blocks/CU.
// R13 change: 256 threads, FOUR waves of 32x64 (2x2) instead of eight 32x32.
// FLOP/LDS-byte 16 -> 21.3 (gemm is LDS-BW-bound: 88 KB LDS traffic vs
// ~774 cyc MFMA per CU-block-step at R12 geometry). 12 waves/CU = m97's
// proven occupancy. acc[2][4]=32 VGPR, launch_bounds(256,3) cap 170: no
// spill (tripwire: WRITE_SIZE stays 24.6 MB).
// Everything else R12-proven: XCD-chunked swizzle, both-sides XOR LDS
// swizzle (0 conflicts), stage-early + __syncthreads double buffer, fused
// prep. Failed alternatives (R6-R11) listed in R12 header: do not revisit.
// ---------------------------------------------------------------------------

#define B_DIM 4096
#define I_DIM 512
#define O_DIM 512
#define N_DIM (O_DIM * 3)   // 1536
#define K_DIM (I_DIM * 3)   // 1536
#define NT (K_DIM / 64)     // 24 K-steps

typedef __attribute__((ext_vector_type(8))) short bf16x8;
typedef __attribute__((ext_vector_type(4))) float f32x4;

__device__ __forceinline__ unsigned short f2bf(float f) {
    unsigned u = __float_as_uint(f);
    unsigned r = (u + 0x7fffu + ((u >> 16) & 1u)) >> 16;  // RNE
    return (unsigned short)r;
}

__device__ __forceinline__ void gload_lds16(const void* g, void* l) {
    __builtin_amdgcn_global_load_lds(
        (const __attribute__((address_space(1))) unsigned*)g,
        (__attribute__((address_space(3))) unsigned*)l, 16, 0, 0);
}

// Cayley table for Cl(3,0,1), metric [0,1,1,1], reference blade order.
struct Cayley {
    float M[16][16][16];
    float rev[16];
    constexpr Cayley() : M{}, rev{} {
        const unsigned masks[16] = {0u, 1u, 2u, 4u, 8u, 3u, 5u, 9u, 6u, 10u,
                                    12u, 7u, 11u, 13u, 14u, 15u};
        int idx_of[16] = {};
        for (int i = 0; i < 16; ++i) idx_of[masks[i]] = i;
        const int metric[4] = {0, 1, 1, 1};
        for (int i = 0; i < 16; ++i) {
            unsigned a = masks[i];
            for (int j = 0; j < 16; ++j) {
                unsigned b = masks[j];
                int swaps = 0;
                for (int jb = 0; jb < 4; ++jb)
                    if ((b >> jb) & 1u)
                        for (int ia = jb + 1; ia < 4; ++ia)
                            if ((a >> ia) & 1u) ++swaps;
                int sign = (swaps & 1) ? -1 : 1;
                unsigned common = a & b;
                for (int g = 0; g < 4; ++g)
                    if ((common >> g) & 1u) sign *= metric[g];
                if (sign != 0) M[i][j][idx_of[a ^ b]] += (float)sign;
            }
            int grade = 0;
            for (int g = 0; g < 4; ++g) grade += (int)((a >> g) & 1u);
            rev[i] = ((grade * (grade - 1) / 2) % 2) ? -1.f : 1.f;
        }
    }
};
constexpr Cayley CAY{};

// ---------------------------------------------------------------------------
// prep: fused pack_x (blocks 0..1535) + build_w/bias (blocks 1536..2047).
// ---------------------------------------------------------------------------
__global__ __launch_bounds__(512) void prep(const float* __restrict__ x,
                                            const float* __restrict__ weight,
                                            const float* __restrict__ action,
                                            const float* __restrict__ e0,
                                            unsigned short* __restrict__ A,
                                            unsigned short* __restrict__ Bw,
                                            float* __restrict__ bias) {
    const int bid = blockIdx.x;
    const int tid = threadIdx.x;

    if (bid < 1536) {
        // ---- pack: A = bf16(x), flat cast (k=i*3+r is exactly x's layout)
        const size_t t = (size_t)bid * 512 + tid;
        const float4* xp = (const float4*)(x + t * 8);
        const float4 v0 = xp[0], v1 = xp[1];
        const float xs[8] = {v0.x, v0.y, v0.z, v0.w, v1.x, v1.y, v1.z, v1.w};
        unsigned short ov[8];
#pragma unroll
        for (int q = 0; q < 8; ++q) ov[q] = f2bf(xs[q]);
        *(uint4*)(A + t * 8) = *(const uint4*)ov;   // 16B store
        return;
    }

    // ---- build: one block per o, one thread per i.
    const int o = bid - 1536;
    const int i = tid;
    const int t = o * I_DIM + i;
    const int wave = tid >> 6, lane = tid & 63;
    __shared__ float red[8][3];

    constexpr int AB[8] = {0, 5, 6, 7, 8, 9, 10, 15};
    constexpr int PB[3] = {11, 12, 13};
    constexpr int RB[4] = {11, 12, 13, 14};

    float a[8];
    const float* ap = action + (size_t)t * 8;
#pragma unroll
    for (int j = 0; j < 8; ++j) a[j] = ap[j];

    float kv[16], kr[16];
#pragma unroll
    for (int j = 0; j < 16; ++j) { kv[j] = 0.f; kr[j] = 0.f; }
#pragma unroll
    for (int j = 0; j < 8; ++j) {
        kv[AB[j]] = a[j];
        kr[AB[j]] = a[j] * CAY.rev[AB[j]];
    }

    float Am[3][16];
#pragma unroll
    for (int pp = 0; pp < 3; ++pp)
#pragma unroll
        for (int q = 0; q < 16; ++q) {
            float s = 0.f;
#pragma unroll
            for (int tt = 0; tt < 16; ++tt) s += CAY.M[q][PB[pp]][tt] * kr[tt];
            Am[pp][q] = s;
        }

    float Bm[16][4];
#pragma unroll
    for (int q = 0; q < 16; ++q)
#pragma unroll
        for (int rr = 0; rr < 4; ++rr) {
            float s = 0.f;
#pragma unroll
            for (int m = 0; m < 16; ++m) s += CAY.M[m][q][RB[rr]] * kv[m];
            Bm[q][rr] = s;
        }

    const float w = weight[t];
    const float e0i = e0[i];
    float sb[3];
#pragma unroll
    for (int pp = 0; pp < 3; ++pp) {
        float r0 = 0.f, r1 = 0.f, r2 = 0.f, r3 = 0.f;
#pragma unroll
        for (int q = 0; q < 16; ++q) {
            r0 += Am[pp][q] * Bm[q][0];
            r1 += Am[pp][q] * Bm[q][1];
            r2 += Am[pp][q] * Bm[q][2];
            r3 += Am[pp][q] * Bm[q][3];
        }
        unsigned short* bp = Bw + (size_t)(o * 3 + pp) * K_DIM + i * 3;
        bp[0] = f2bf(w * r0);
        bp[1] = f2bf(w * r1);
        bp[2] = f2bf(w * r2);
        sb[pp] = w * r3 * e0i;
    }

#pragma unroll
    for (int off = 32; off; off >>= 1) {
#pragma unroll
        for (int pp = 0; pp < 3; ++pp) sb[pp] += __shfl_down(sb[pp], off, 64);
    }
    if (lane == 0) {
#pragma unroll
        for (int pp = 0; pp < 3; ++pp) red[wave][pp] = sb[pp];
    }
    __syncthreads();
    if (tid == 0) {
#pragma unroll
        for (int pp = 0; pp < 3; ++pp) {
            float s = 0.f;
#pragma unroll
            for (int wv = 0; wv < 8; ++wv) s += red[wv][pp];
            bias[o * 3 + pp] = s;
        }
    }
}

// ---------------------------------------------------------------------------
// gemm: C[m][n] = sum_k A[m][k]*Bw[n][k] + bias[n].
// 256 threads, 4 waves (2x2), wave tile 32x64 (acc[2][4]).
// ---------------------------------------------------------------------------
__global__ __launch_bounds__(256, 3) void gemm_bf16(
        const unsigned short* __restrict__ A,
        const unsigned short* __restrict__ Bw,
        const float* __restrict__ bias,
        float* __restrict__ C) {
    __shared__ unsigned short As0[64 * 64], As1[64 * 64];    //  8 KB each
    __shared__ unsigned short Bs0[128 * 64], Bs1[128 * 64];  // 16 KB each
    // 48 KB total -> 3 blocks/CU (12 waves/CU, m97's proven occupancy).

    const int tid = threadIdx.x;
    const int wave = tid >> 6, lane = tid & 63;

    // XCD-chunked bijective swizzle (768 % 8 == 0), m-tile-major.
    const int bid = blockIdx.x;
    const int swz = (bid & 7) * 96 + (bid >> 3);
    const int mt = swz / 12, nt = swz - mt * 12;
    const int m0 = mt * 64, n0 = nt * 128;
    const int wr = wave >> 1, wc = wave & 1;     // 2x2 wave grid, 32x64 each

    // staging: 16B segs; seg s -> LDS byte s*16 (linear); global col-seg
    // = (s&7)^(row&7)   [both-sides XOR swizzle]. A: 512 segs (2/thread),
    // B: 1024 segs (4/thread); 6 loads/thread, uniform.
    const unsigned short* aSrc[2];
    int aOff[2];
#pragma unroll
    for (int q = 0; q < 2; ++q) {
        const int s = tid + q * 256;
        aSrc[q] = A + (size_t)(m0 + (s >> 3)) * K_DIM +
                  (((s & 7) ^ ((s >> 3) & 7)) * 8);
        aOff[q] = s * 8;
    }
    const unsigned short* bSrc[4];
    int bOff[4];
#pragma unroll
    for (int q = 0; q < 4; ++q) {
        const int s = tid + q * 256;
        bSrc[q] = Bw + (size_t)(n0 + (s >> 3)) * K_DIM +
                  (((s & 7) ^ ((s >> 3) & 7)) * 8);
        bOff[q] = s * 8;
    }

    // fragment read: row r, global col-seg g -> elem r*64 + ((g)^(r&7))*8
    const int frow = lane & 15;
    const int g0 = lane >> 4;

    f32x4 acc[2][4] = {};

#define STAGE(AS, BS, K0)                                    \
    do {                                                     \
        gload_lds16(aSrc[0] + (K0), (AS) + aOff[0]);         \
        gload_lds16(aSrc[1] + (K0), (AS) + aOff[1]);         \
        _Pragma("unroll")                                    \
        for (int q = 0; q < 4; ++q)                          \
            gload_lds16(bSrc[q] + (K0), (BS) + bOff[q]);     \
    } while (0)

#define COMPUTE(AS, BS)                                                        \
    do {                                                                       \
        bf16x8 af[2][2], bfr[2][4];                                            \
        _Pragma("unroll")                                                      \
        for (int kh = 0; kh < 2; ++kh) {                                       \
            _Pragma("unroll")                                                  \
            for (int mi = 0; mi < 2; ++mi) {                                   \
                const int r = wr * 32 + mi * 16 + frow;                        \
                af[kh][mi] =                                                   \
                    *(const bf16x8*)&(AS)[r * 64 + ((g0 + kh * 4) ^ (r & 7)) * 8]; \
            }                                                                  \
            _Pragma("unroll")                                                  \
            for (int ni = 0; ni < 4; ++ni) {                                   \
                const int r = wc * 64 + ni * 16 + frow;                        \
                bfr[kh][ni] =                                                  \
                    *(const bf16x8*)&(BS)[r * 64 + ((g0 + kh * 4) ^ (r & 7)) * 8]; \
            }                                                                  \
        }                                                                      \
        _Pragma("unroll")                                                      \
        for (int kh = 0; kh < 2; ++kh)                                         \
            _Pragma("unroll")                                                  \
            for (int mi = 0; mi < 2; ++mi)                                     \
                _Pragma("unroll")                                              \
                for (int ni = 0; ni < 4; ++ni)                                 \
                    acc[mi][ni] = __builtin_amdgcn_mfma_f32_16x16x32_bf16(     \
                        af[kh][mi], bfr[kh][ni], acc[mi][ni], 0, 0, 0);        \
    } while (0)

    STAGE(As0, Bs0, 0);
    __syncthreads();                       // buf0 ready

#pragma unroll 1
    for (int t = 0; t < NT - 2; t += 2) {
        STAGE(As1, Bs1, (t + 1) * 64);     // issue next-tile loads FIRST
        COMPUTE(As0, Bs0);                 // MFMA + other waves hide latency
        __syncthreads();
        STAGE(As0, Bs0, (t + 2) * 64);
        COMPUTE(As1, Bs1);
        __syncthreads();
    }
    STAGE(As1, Bs1, (NT - 1) * 64);
    COMPUTE(As0, Bs0);
    __syncthreads();
    COMPUTE(As1, Bs1);

#undef STAGE
#undef COMPUTE

    // epilogue: C/D layout col = lane&15, row = (lane>>4)*4 + j; add bias[n]
    const int crow = (lane >> 4) * 4;
    const int ccol = lane & 15;
#pragma unroll
    for (int mi = 0; mi < 2; ++mi)
#pragma unroll
        for (int ni = 0; ni < 4; ++ni) {
            const int n = n0 + wc * 64 + ni * 16 + ccol;
            const float bv = bias[n];
            float* cp = C + (size_t)(m0 + wr * 32 + mi * 16 + crow) * N_DIM + n;
#pragma unroll
            for (int j = 0; j < 4; ++j) cp[(size_t)j * N_DIM] = acc[mi][ni][j] + bv;
        }
}

// ---------------------------------------------------------------------------
extern "C" void kernel_launch(void* const* d_in, const int* in_sizes, int n_in,
                              void* d_out, int out_size, void* d_ws, size_t ws_size,
                              hipStream_t stream) {
    const float* x      = (const float*)d_in[0];  // (4096, 512, 3)
    const float* weight = (const float*)d_in[1];  // (512, 512)
    const float* action = (const float*)d_in[2];  // (512, 512, 8)
    const float* e0     = (const float*)d_in[3];  // (512, 1)
    float* out = (float*)d_out;                   // (4096, 512, 3)

    unsigned short* Bw = (unsigned short*)d_ws;                 // 4.7 MB
    unsigned short* Ap = Bw + (size_t)N_DIM * K_DIM;            // 12.6 MB
    float* bias = (float*)(Ap + (size_t)B_DIM * K_DIM);         // 1536 f32

    hipLaunchKernelGGL(prep, dim3(2048), dim3(512), 0, stream,
                       x, weight, action, e0, Ap, Bw, bias);
    hipLaunchKernelGGL(gemm_bf16, dim3(768), dim3(256), 0, stream,
                       Ap, Bw, bias, out);
}